// Round 1
// baseline (244.210 us; speedup 1.0000x reference)
//
#include <hip/hip_runtime.h>

// SSAaligner: s[i,j] = -sum_d |x[i,d]-y[j,d]|, x=(N,D) from z_x(D,N), y=(M,D) from z_y(D,M)
// a = softmax_rows(s), b = softmax_cols(s), u = a+b-a*b, out = sum(u*s)/sum(u)
// D=256, N=M=1024. fp32 in, fp32 scalar out.

#define DD  256
#define NN  1024   // rows == cols (symmetric sizes)
#define TI  8      // rows per block
#define BLK 256    // threads per block (4 waves); each thread owns 4 contiguous cols

__device__ __forceinline__ float blockReduceMax(float v, float* red) {
  #pragma unroll
  for (int off = 32; off > 0; off >>= 1)
    v = fmaxf(v, __shfl_down(v, off, 64));
  const int wid = threadIdx.x >> 6, lane = threadIdx.x & 63;
  __syncthreads();                  // protect red[] from previous use
  if (lane == 0) red[wid] = v;
  __syncthreads();
  return fmaxf(fmaxf(red[0], red[1]), fmaxf(red[2], red[3]));
}

__device__ __forceinline__ float blockReduceSum(float v, float* red) {
  #pragma unroll
  for (int off = 32; off > 0; off >>= 1)
    v += __shfl_down(v, off, 64);
  const int wid = threadIdx.x >> 6, lane = threadIdx.x & 63;
  __syncthreads();
  if (lane == 0) red[wid] = v;
  __syncthreads();
  return red[0] + red[1] + red[2] + red[3];
}

// Computes the L1-distance tile for rows [i0, i0+TI) of the matrix whose
// "row" operand is X (layout (D, L): X[d*L + i]) against all 1024 columns
// from Y (layout (D, L)). acc[r][c] = sum_d |X[d][i0+r] - Y[d][4t+c]|.
__device__ __forceinline__ void computeTile(const float* __restrict__ X,
                                            const float* __restrict__ Y,
                                            int i0, int t,
                                            float (&xs)[TI][DD],
                                            float (&acc)[TI][4]) {
  for (int k = t; k < TI * DD; k += BLK) {
    const int r = k >> 8, d = k & (DD - 1);
    xs[r][d] = X[d * NN + i0 + r];
  }
  __syncthreads();
  #pragma unroll
  for (int r = 0; r < TI; ++r)
    #pragma unroll
    for (int c = 0; c < 4; ++c) acc[r][c] = 0.f;

  const float4* __restrict__ Y4 = (const float4*)Y;
  for (int d = 0; d < DD; ++d) {
    const float4 yv = Y4[d * (NN / 4) + t];
    #pragma unroll
    for (int r = 0; r < TI; ++r) {
      const float xv = xs[r][d];
      acc[r][0] += fabsf(xv - yv.x);
      acc[r][1] += fabsf(xv - yv.y);
      acc[r][2] += fabsf(xv - yv.z);
      acc[r][3] += fabsf(xv - yv.w);
    }
  }
}

// Row-softmax stats for the distance matrix with rows from X, cols from Y.
// Called as (zx, zy) -> rmax/rsum of S; as (zy, zx) -> cmax/csum of S (= row
// stats of S^T, since |x-y| is symmetric).
__global__ __launch_bounds__(BLK)
void stats_kernel(const float* __restrict__ X, const float* __restrict__ Y,
                  float* __restrict__ omax, float* __restrict__ osum) {
  __shared__ float xs[TI][DD];
  __shared__ float red[4];
  const int t = threadIdx.x;
  const int i0 = blockIdx.x * TI;
  float acc[TI][4];
  computeTile(X, Y, i0, t, xs, acc);

  #pragma unroll
  for (int r = 0; r < TI; ++r) {
    // s = -acc
    float m = fmaxf(fmaxf(-acc[r][0], -acc[r][1]), fmaxf(-acc[r][2], -acc[r][3]));
    m = blockReduceMax(m, red);
    float p = expf(-acc[r][0] - m) + expf(-acc[r][1] - m) +
              expf(-acc[r][2] - m) + expf(-acc[r][3] - m);
    p = blockReduceSum(p, red);
    if (t == 0) { omax[i0 + r] = m; osum[i0 + r] = p; }
  }
}

__global__ __launch_bounds__(BLK)
void final_kernel(const float* __restrict__ X, const float* __restrict__ Y,
                  const float* __restrict__ rmax, const float* __restrict__ rsum,
                  const float* __restrict__ cmax, const float* __restrict__ csum,
                  float* __restrict__ accum) {
  __shared__ float xs[TI][DD];
  __shared__ float red[4];
  const int t = threadIdx.x;
  const int i0 = blockIdx.x * TI;
  float acc[TI][4];
  computeTile(X, Y, i0, t, xs, acc);

  float un = 0.f, ud = 0.f;
  #pragma unroll
  for (int r = 0; r < TI; ++r) {
    const int i = i0 + r;
    const float rm = rmax[i];
    const float rrs = 1.f / rsum[i];
    #pragma unroll
    for (int c = 0; c < 4; ++c) {
      const int j = 4 * t + c;
      const float s = -acc[r][c];
      const float a = expf(s - rm) * rrs;
      const float b = expf(s - cmax[j]) / csum[j];
      const float u = a + b - a * b;
      un += u * s;
      ud += u;
    }
  }
  un = blockReduceSum(un, red);
  ud = blockReduceSum(ud, red);
  if (t == 0) {
    atomicAdd(&accum[0], un);
    atomicAdd(&accum[1], ud);
  }
}

__global__ void zero_kernel(float* __restrict__ accum) {
  if (threadIdx.x < 2) accum[threadIdx.x] = 0.f;
}

__global__ void finalize_kernel(const float* __restrict__ accum, float* __restrict__ out) {
  out[0] = accum[0] / accum[1];
}

extern "C" void kernel_launch(void* const* d_in, const int* in_sizes, int n_in,
                              void* d_out, int out_size, void* d_ws, size_t ws_size,
                              hipStream_t stream) {
  const float* zx = (const float*)d_in[0];   // (1, D, N) -> X[d*N + i]
  const float* zy = (const float*)d_in[1];   // (1, D, M) -> Y[d*M + j]
  float* ws    = (float*)d_ws;
  float* accum = ws;                 // [0]=num, [1]=den
  float* rmax  = ws + 16;            // 1024
  float* rsum  = ws + 16 + 1024;     // 1024
  float* cmax  = ws + 16 + 2048;     // 1024
  float* csum  = ws + 16 + 3072;     // 1024  (total ~16.5 KB of ws)
  float* out   = (float*)d_out;

  zero_kernel<<<1, 64, 0, stream>>>(accum);
  stats_kernel<<<NN / TI, BLK, 0, stream>>>(zx, zy, rmax, rsum);   // row stats
  stats_kernel<<<NN / TI, BLK, 0, stream>>>(zy, zx, cmax, csum);   // col stats (S^T)
  final_kernel<<<NN / TI, BLK, 0, stream>>>(zx, zy, rmax, rsum, cmax, csum, accum);
  finalize_kernel<<<1, 1, 0, stream>>>(accum, out);
}

// Round 2
// 170.379 us; speedup vs baseline: 1.4333x; 1.4333x over previous
//
#include <hip/hip_runtime.h>
#include <math.h>

// SSAaligner: s[i,j] = -sum_d |x[i,d]-y[j,d]|, x from z_x(D,N), y from z_y(D,M)
// a = softmax_rows(s), b = softmax_cols(s), u = a+b-a*b, out = sum(u*s)/sum(u)
// D=256, N=M=1024. fp32 in, fp32 scalar out.
//
// R2: occupancy fix. Grid 2048 blocks (8 col-chunks x 128 row-tiles x 2 sides)
// for the fused stats pass; 1024 blocks for the final pass. Partial row stats
// per 128-col chunk, merged by a tiny combine kernel.

#define DD  256
#define NN  1024
#define TI  8      // rows per block
#define TJ  128    // cols per block
#define NCH (NN / TJ)   // 8 col chunks
#define BLK 256

// ---------------------------------------------------------------------------
// Fast path (needs ~148 KB of ws)
// ---------------------------------------------------------------------------

// side 0: rows of S (x rows vs y cols) -> row-softmax partials
// side 1: rows of S^T (y rows vs x cols) -> col-softmax partials (|.| symmetric)
__global__ __launch_bounds__(BLK)
void stats2_kernel(const float* __restrict__ zx, const float* __restrict__ zy,
                   float* __restrict__ partM, float* __restrict__ partS) {
  const int side = blockIdx.z;
  const float* __restrict__ X = side ? zy : zx;
  const float* __restrict__ Y = side ? zx : zy;
  const int j0 = blockIdx.x * TJ;
  const int i0 = blockIdx.y * TI;
  const int t  = threadIdx.x;
  const int rg = t >> 5;   // row 0..7 within tile
  const int c  = t & 31;   // col-quad 0..31 (4 cols each)

  __shared__ float xs[TI * DD];   // xs[d*8 + r], staged stride-1
  for (int k = t; k < TI * DD; k += BLK)
    xs[k] = X[(k >> 3) * NN + i0 + (k & 7)];
  __syncthreads();

  const float4* __restrict__ Y4 = (const float4*)Y;
  const int yb = (j0 >> 2) + c;
  float4 acc = make_float4(0.f, 0.f, 0.f, 0.f);
  #pragma unroll 8
  for (int d = 0; d < DD; ++d) {
    const float4 yv = Y4[d * (NN / 4) + yb];
    const float xv = xs[d * TI + rg];
    acc.x += fabsf(xv - yv.x);
    acc.y += fabsf(xv - yv.y);
    acc.z += fabsf(xv - yv.z);
    acc.w += fabsf(xv - yv.w);
  }

  // s = -acc; reduce over the 32 lanes owning this row's chunk
  float m = fmaxf(fmaxf(-acc.x, -acc.y), fmaxf(-acc.z, -acc.w));
  #pragma unroll
  for (int off = 16; off > 0; off >>= 1)
    m = fmaxf(m, __shfl_down(m, off, 32));
  m = __shfl(m, 0, 32);
  float p = expf(-acc.x - m) + expf(-acc.y - m) +
            expf(-acc.z - m) + expf(-acc.w - m);
  #pragma unroll
  for (int off = 16; off > 0; off >>= 1)
    p += __shfl_down(p, off, 32);

  if (c == 0) {
    const int idx = side * (NCH * NN) + blockIdx.x * NN + (i0 + rg);
    partM[idx] = m;
    partS[idx] = p;
  }
}

// 8 blocks x 256 threads: one thread per (side, row/col)
__global__ __launch_bounds__(BLK)
void combine_kernel(const float* __restrict__ partM, const float* __restrict__ partS,
                    float* __restrict__ rmax, float* __restrict__ rsum,
                    float* __restrict__ cmax, float* __restrict__ csum,
                    float* __restrict__ accum) {
  const int gid = blockIdx.x * BLK + threadIdx.x;   // 0..2047
  if (gid == 0) { accum[0] = 0.f; accum[1] = 0.f; }
  const int sd = gid >> 10;
  const int i  = gid & (NN - 1);
  float mk[NCH], sk[NCH];
  #pragma unroll
  for (int k = 0; k < NCH; ++k) {
    mk[k] = partM[sd * (NCH * NN) + k * NN + i];
    sk[k] = partS[sd * (NCH * NN) + k * NN + i];
  }
  float m = mk[0];
  #pragma unroll
  for (int k = 1; k < NCH; ++k) m = fmaxf(m, mk[k]);
  float s = 0.f;
  #pragma unroll
  for (int k = 0; k < NCH; ++k) s += expf(mk[k] - m) * sk[k];
  if (sd == 0) { rmax[i] = m; rsum[i] = s; }
  else         { cmax[i] = m; csum[i] = s; }
}

__global__ __launch_bounds__(BLK)
void final2_kernel(const float* __restrict__ zx, const float* __restrict__ zy,
                   const float* __restrict__ rmax, const float* __restrict__ rsum,
                   const float* __restrict__ cmax, const float* __restrict__ csum,
                   float* __restrict__ accum) {
  const int j0 = blockIdx.x * TJ;
  const int i0 = blockIdx.y * TI;
  const int t  = threadIdx.x;
  const int rg = t >> 5;
  const int c  = t & 31;

  __shared__ float xs[TI * DD];
  __shared__ float redn[4], redd[4];
  for (int k = t; k < TI * DD; k += BLK)
    xs[k] = zx[(k >> 3) * NN + i0 + (k & 7)];
  __syncthreads();

  const float4* __restrict__ Y4 = (const float4*)zy;
  const int yb = (j0 >> 2) + c;
  float4 acc = make_float4(0.f, 0.f, 0.f, 0.f);
  #pragma unroll 8
  for (int d = 0; d < DD; ++d) {
    const float4 yv = Y4[d * (NN / 4) + yb];
    const float xv = xs[d * TI + rg];
    acc.x += fabsf(xv - yv.x);
    acc.y += fabsf(xv - yv.y);
    acc.z += fabsf(xv - yv.z);
    acc.w += fabsf(xv - yv.w);
  }

  const int i = i0 + rg;
  const float rm = rmax[i];
  const float rr = 1.f / rsum[i];
  const float4 cm = ((const float4*)cmax)[yb];
  const float4 cs = ((const float4*)csum)[yb];

  float un = 0.f, ud = 0.f;
  {
    const float s = -acc.x;
    const float a = expf(s - rm) * rr;
    const float b = expf(s - cm.x) / cs.x;
    const float u = a + b - a * b;
    un += u * s; ud += u;
  }
  {
    const float s = -acc.y;
    const float a = expf(s - rm) * rr;
    const float b = expf(s - cm.y) / cs.y;
    const float u = a + b - a * b;
    un += u * s; ud += u;
  }
  {
    const float s = -acc.z;
    const float a = expf(s - rm) * rr;
    const float b = expf(s - cm.z) / cs.z;
    const float u = a + b - a * b;
    un += u * s; ud += u;
  }
  {
    const float s = -acc.w;
    const float a = expf(s - rm) * rr;
    const float b = expf(s - cm.w) / cs.w;
    const float u = a + b - a * b;
    un += u * s; ud += u;
  }

  #pragma unroll
  for (int off = 32; off > 0; off >>= 1) {
    un += __shfl_down(un, off, 64);
    ud += __shfl_down(ud, off, 64);
  }
  const int w = t >> 6;
  if ((t & 63) == 0) { redn[w] = un; redd[w] = ud; }
  __syncthreads();
  if (t == 0) {
    atomicAdd(&accum[0], redn[0] + redn[1] + redn[2] + redn[3]);
    atomicAdd(&accum[1], redd[0] + redd[1] + redd[2] + redd[3]);
  }
}

__global__ void finalize_kernel(const float* __restrict__ accum, float* __restrict__ out) {
  out[0] = accum[0] / accum[1];
}

// ---------------------------------------------------------------------------
// Fallback path (round-1 kernels, needs only ~16.5 KB of ws)
// ---------------------------------------------------------------------------

__device__ __forceinline__ float blockReduceMaxOld(float v, float* red) {
  #pragma unroll
  for (int off = 32; off > 0; off >>= 1)
    v = fmaxf(v, __shfl_down(v, off, 64));
  const int wid = threadIdx.x >> 6, lane = threadIdx.x & 63;
  __syncthreads();
  if (lane == 0) red[wid] = v;
  __syncthreads();
  return fmaxf(fmaxf(red[0], red[1]), fmaxf(red[2], red[3]));
}

__device__ __forceinline__ float blockReduceSumOld(float v, float* red) {
  #pragma unroll
  for (int off = 32; off > 0; off >>= 1)
    v += __shfl_down(v, off, 64);
  const int wid = threadIdx.x >> 6, lane = threadIdx.x & 63;
  __syncthreads();
  if (lane == 0) red[wid] = v;
  __syncthreads();
  return red[0] + red[1] + red[2] + red[3];
}

__device__ __forceinline__ void computeTileOld(const float* __restrict__ X,
                                               const float* __restrict__ Y,
                                               int i0, int t,
                                               float (&xs)[TI][DD],
                                               float (&acc)[TI][4]) {
  for (int k = t; k < TI * DD; k += BLK) {
    const int r = k >> 8, d = k & (DD - 1);
    xs[r][d] = X[d * NN + i0 + r];
  }
  __syncthreads();
  #pragma unroll
  for (int r = 0; r < TI; ++r)
    #pragma unroll
    for (int c = 0; c < 4; ++c) acc[r][c] = 0.f;
  const float4* __restrict__ Y4 = (const float4*)Y;
  for (int d = 0; d < DD; ++d) {
    const float4 yv = Y4[d * (NN / 4) + t];
    #pragma unroll
    for (int r = 0; r < TI; ++r) {
      const float xv = xs[r][d];
      acc[r][0] += fabsf(xv - yv.x);
      acc[r][1] += fabsf(xv - yv.y);
      acc[r][2] += fabsf(xv - yv.z);
      acc[r][3] += fabsf(xv - yv.w);
    }
  }
}

__global__ __launch_bounds__(BLK)
void stats_kernel_old(const float* __restrict__ X, const float* __restrict__ Y,
                      float* __restrict__ omax, float* __restrict__ osum) {
  __shared__ float xs[TI][DD];
  __shared__ float red[4];
  const int t = threadIdx.x;
  const int i0 = blockIdx.x * TI;
  float acc[TI][4];
  computeTileOld(X, Y, i0, t, xs, acc);
  #pragma unroll
  for (int r = 0; r < TI; ++r) {
    float m = fmaxf(fmaxf(-acc[r][0], -acc[r][1]), fmaxf(-acc[r][2], -acc[r][3]));
    m = blockReduceMaxOld(m, red);
    float p = expf(-acc[r][0] - m) + expf(-acc[r][1] - m) +
              expf(-acc[r][2] - m) + expf(-acc[r][3] - m);
    p = blockReduceSumOld(p, red);
    if (t == 0) { omax[i0 + r] = m; osum[i0 + r] = p; }
  }
}

__global__ __launch_bounds__(BLK)
void final_kernel_old(const float* __restrict__ X, const float* __restrict__ Y,
                      const float* __restrict__ rmax, const float* __restrict__ rsum,
                      const float* __restrict__ cmax, const float* __restrict__ csum,
                      float* __restrict__ accum) {
  __shared__ float xs[TI][DD];
  __shared__ float red[4];
  const int t = threadIdx.x;
  const int i0 = blockIdx.x * TI;
  float acc[TI][4];
  computeTileOld(X, Y, i0, t, xs, acc);
  float un = 0.f, ud = 0.f;
  #pragma unroll
  for (int r = 0; r < TI; ++r) {
    const int i = i0 + r;
    const float rm = rmax[i];
    const float rrs = 1.f / rsum[i];
    #pragma unroll
    for (int c = 0; c < 4; ++c) {
      const int j = 4 * t + c;
      const float s = -acc[r][c];
      const float a = expf(s - rm) * rrs;
      const float b = expf(s - cmax[j]) / csum[j];
      const float u = a + b - a * b;
      un += u * s;
      ud += u;
    }
  }
  un = blockReduceSumOld(un, red);
  ud = blockReduceSumOld(ud, red);
  if (t == 0) {
    atomicAdd(&accum[0], un);
    atomicAdd(&accum[1], ud);
  }
}

__global__ void zero_kernel(float* __restrict__ accum) {
  if (threadIdx.x < 2) accum[threadIdx.x] = 0.f;
}

// ---------------------------------------------------------------------------

extern "C" void kernel_launch(void* const* d_in, const int* in_sizes, int n_in,
                              void* d_out, int out_size, void* d_ws, size_t ws_size,
                              hipStream_t stream) {
  const float* zx = (const float*)d_in[0];   // (1, D, N): X[d*N + i]
  const float* zy = (const float*)d_in[1];   // (1, D, M): Y[d*M + j]
  float* ws  = (float*)d_ws;
  float* out = (float*)d_out;

  // fast-path ws layout (floats)
  float* accum = ws;                         // [0]=num, [1]=den
  float* partM = ws + 16;                    // 2*8*1024
  float* partS = partM + 2 * NCH * NN;       // 2*8*1024
  float* rmax  = partS + 2 * NCH * NN;       // 1024
  float* rsum  = rmax + NN;
  float* cmax  = rsum + NN;
  float* csum  = cmax + NN;
  const size_t need = (size_t)((csum + NN) - ws) * sizeof(float);  // ~148 KB

  if (ws_size >= need) {
    dim3 sgrid(NCH, NN / TI, 2);             // 2048 blocks
    stats2_kernel<<<sgrid, BLK, 0, stream>>>(zx, zy, partM, partS);
    combine_kernel<<<(2 * NN) / BLK, BLK, 0, stream>>>(partM, partS,
                                                       rmax, rsum, cmax, csum, accum);
    dim3 fgrid(NCH, NN / TI);                // 1024 blocks
    final2_kernel<<<fgrid, BLK, 0, stream>>>(zx, zy, rmax, rsum, cmax, csum, accum);
    finalize_kernel<<<1, 1, 0, stream>>>(accum, out);
  } else {
    // round-1 fallback (ws >= ~16.5 KB)
    float* frmax = ws + 16;
    float* frsum = frmax + NN;
    float* fcmax = frsum + NN;
    float* fcsum = fcmax + NN;
    zero_kernel<<<1, 64, 0, stream>>>(accum);
    stats_kernel_old<<<NN / TI, BLK, 0, stream>>>(zx, zy, frmax, frsum);
    stats_kernel_old<<<NN / TI, BLK, 0, stream>>>(zy, zx, fcmax, fcsum);
    final_kernel_old<<<NN / TI, BLK, 0, stream>>>(zx, zy, frmax, frsum, fcmax, fcsum, accum);
    finalize_kernel<<<1, 1, 0, stream>>>(accum, out);
  }
}

// Round 3
// 125.177 us; speedup vs baseline: 1.9509x; 1.3611x over previous
//
#include <hip/hip_runtime.h>
#include <math.h>

// SSAaligner: s[i,j] = -sum_d |x[i,d]-y[j,d]|, x from z_x(D,N), y from z_y(D,M)
// a = softmax_rows(s), b = softmax_cols(s), u = a+b-a*b, out = sum(u*s)/sum(u)
// D=256, N=M=1024. fp32 in, fp32 scalar out.
//
// R3: materialize S once (d-split x4 partial buffers, R=8 register blocking ->
// ~32B/cyc L1 demand, VALU-bound), then cheap BW-bound softmax passes.

#define DD 256
#define NN 1024
#define DS 4
#define CH (DD / DS)   // 64 d's per chunk

// ---------------- reductions ----------------
__device__ __forceinline__ float waveMax(float v) {
  #pragma unroll
  for (int off = 32; off; off >>= 1) v = fmaxf(v, __shfl_xor(v, off, 64));
  return v;
}
__device__ __forceinline__ float waveSum(float v) {
  #pragma unroll
  for (int off = 32; off; off >>= 1) v += __shfl_xor(v, off, 64);
  return v;
}
__device__ __forceinline__ float blockMax(float v, float* red) {
  v = waveMax(v);
  __syncthreads();
  if ((threadIdx.x & 63) == 0) red[threadIdx.x >> 6] = v;
  __syncthreads();
  return fmaxf(fmaxf(red[0], red[1]), fmaxf(red[2], red[3]));
}
__device__ __forceinline__ float blockSum(float v, float* red) {
  v = waveSum(v);
  __syncthreads();
  if ((threadIdx.x & 63) == 0) red[threadIdx.x >> 6] = v;
  __syncthreads();
  return red[0] + red[1] + red[2] + red[3];
}

// ---------------- fast path: materialized S ----------------

// Tile 64 rows x 128 cols x 64 d. Each thread: 8 rows x 4 cols accumulators.
// grid (8 coltiles, 16 rowtiles, 4 d-chunks) = 512 blocks -> 2 blocks/CU.
__global__ __launch_bounds__(256)
void scompute_kernel(const float* __restrict__ zx, const float* __restrict__ zy,
                     float* __restrict__ Sp, float* __restrict__ accum) {
  const int h  = blockIdx.z;
  const int i0 = blockIdx.y * 64;
  const int j0 = blockIdx.x * 128;
  const int t  = threadIdx.x;
  const int g  = t >> 5;   // row group (8 rows each)
  const int c  = t & 31;   // col quad
  if ((blockIdx.x | blockIdx.y | blockIdx.z) == 0 && t == 0) {
    accum[0] = 0.f; accum[1] = 0.f;
  }

  __shared__ float xs[CH * 64];   // xs[d*64 + r]
  {
    const float4* __restrict__ X4 = (const float4*)zx;
    float4* xs4 = (float4*)xs;
    #pragma unroll
    for (int k = t; k < CH * 16; k += 256)
      xs4[k] = X4[(h * CH + (k >> 4)) * (NN / 4) + (i0 >> 2) + (k & 15)];
  }
  __syncthreads();

  float acc[8][4];
  #pragma unroll
  for (int r = 0; r < 8; ++r)
    #pragma unroll
    for (int q = 0; q < 4; ++q) acc[r][q] = 0.f;

  const float4* __restrict__ yp =
      (const float4*)zy + (size_t)(h * CH) * (NN / 4) + (j0 >> 2) + c;
  #pragma unroll 4
  for (int d = 0; d < CH; ++d) {
    const float4 yv = yp[d * (NN / 4)];
    const float* xr = xs + d * 64 + g * 8;
    #pragma unroll
    for (int r = 0; r < 8; ++r) {
      const float xv = xr[r];
      acc[r][0] += fabsf(xv - yv.x);
      acc[r][1] += fabsf(xv - yv.y);
      acc[r][2] += fabsf(xv - yv.z);
      acc[r][3] += fabsf(xv - yv.w);
    }
  }

  float4* __restrict__ S4 = (float4*)Sp + (size_t)h * (NN * NN / 4);
  #pragma unroll
  for (int r = 0; r < 8; ++r)
    S4[(i0 + g * 8 + r) * (NN / 4) + (j0 >> 2) + c] =
        make_float4(acc[r][0], acc[r][1], acc[r][2], acc[r][3]);
}

// 256 blocks x 4 rows: sum partials (write back to buf0), full row max/sumexp.
__global__ __launch_bounds__(256)
void rowstats_kernel(float* __restrict__ Sp,
                     float* __restrict__ rmax, float* __restrict__ rsum) {
  __shared__ float red[4];
  const int t = threadIdx.x;
  const int row0 = blockIdx.x * 4;
  float4* S4 = (float4*)Sp;
  #pragma unroll
  for (int rr = 0; rr < 4; ++rr) {
    const int row = row0 + rr;
    float4 p = S4[row * (NN / 4) + t];
    #pragma unroll
    for (int hh = 1; hh < DS; ++hh) {
      const float4 q = S4[hh * (NN * NN / 4) + row * (NN / 4) + t];
      p.x += q.x; p.y += q.y; p.z += q.z; p.w += q.w;
    }
    S4[row * (NN / 4) + t] = p;   // S (positive L1 dist) now lives in buf0
    float m = fmaxf(fmaxf(-p.x, -p.y), fmaxf(-p.z, -p.w));
    m = blockMax(m, red);
    float l = __expf(-p.x - m) + __expf(-p.y - m) +
              __expf(-p.z - m) + __expf(-p.w - m);
    l = blockSum(l, red);
    if (t == 0) { rmax[row] = m; rsum[row] = l; }
  }
}

// 64 blocks x 16 rows: partial col stats (two passes over 16 rows).
__global__ __launch_bounds__(256)
void colstats_kernel(const float* __restrict__ Sp,
                     float* __restrict__ pm, float* __restrict__ ps) {
  const int t = threadIdx.x;
  const int r0 = blockIdx.x * 16;
  const float4* S4 = (const float4*)Sp;
  float4 m = make_float4(-1e30f, -1e30f, -1e30f, -1e30f);
  #pragma unroll 4
  for (int i = 0; i < 16; ++i) {
    const float4 p = S4[(r0 + i) * (NN / 4) + t];
    m.x = fmaxf(m.x, -p.x); m.y = fmaxf(m.y, -p.y);
    m.z = fmaxf(m.z, -p.z); m.w = fmaxf(m.w, -p.w);
  }
  float4 l = make_float4(0.f, 0.f, 0.f, 0.f);
  #pragma unroll 4
  for (int i = 0; i < 16; ++i) {
    const float4 p = S4[(r0 + i) * (NN / 4) + t];
    l.x += __expf(-p.x - m.x); l.y += __expf(-p.y - m.y);
    l.z += __expf(-p.z - m.z); l.w += __expf(-p.w - m.w);
  }
  ((float4*)pm)[blockIdx.x * (NN / 4) + t] = m;
  ((float4*)ps)[blockIdx.x * (NN / 4) + t] = l;
}

// 4 blocks x 256: merge the 64 row-chunk partials per column.
__global__ __launch_bounds__(256)
void colcombine_kernel(const float* __restrict__ pm, const float* __restrict__ ps,
                       float* __restrict__ cmax, float* __restrict__ csum) {
  const int j = blockIdx.x * 256 + threadIdx.x;
  float m = -1e30f;
  #pragma unroll 8
  for (int k = 0; k < 64; ++k) m = fmaxf(m, pm[k * NN + j]);
  float l = 0.f;
  #pragma unroll 8
  for (int k = 0; k < 64; ++k) l += __expf(pm[k * NN + j] - m) * ps[k * NN + j];
  cmax[j] = m; csum[j] = l;
}

// 256 blocks x 4 rows: u = a+b-a*b, reduce sum(u*s), sum(u).
__global__ __launch_bounds__(256)
void final_kernel(const float* __restrict__ Sp,
                  const float* __restrict__ rmax, const float* __restrict__ rsum,
                  const float* __restrict__ cmax, const float* __restrict__ csum,
                  float* __restrict__ accum) {
  __shared__ float redn[4], redd[4];
  const int t = threadIdx.x;
  const int row0 = blockIdx.x * 4;
  const float4* S4 = (const float4*)Sp;
  const float4 cm = ((const float4*)cmax)[t];
  const float4 cs = ((const float4*)csum)[t];
  float un = 0.f, ud = 0.f;
  #pragma unroll
  for (int rr = 0; rr < 4; ++rr) {
    const int row = row0 + rr;
    const float rm = rmax[row];
    const float ri = 1.f / rsum[row];
    const float4 p = S4[row * (NN / 4) + t];
    {
      const float s = -p.x;
      const float a = __expf(s - rm) * ri;
      const float b = __expf(s - cm.x) / cs.x;
      const float u = a + b - a * b;
      un += u * s; ud += u;
    }
    {
      const float s = -p.y;
      const float a = __expf(s - rm) * ri;
      const float b = __expf(s - cm.y) / cs.y;
      const float u = a + b - a * b;
      un += u * s; ud += u;
    }
    {
      const float s = -p.z;
      const float a = __expf(s - rm) * ri;
      const float b = __expf(s - cm.z) / cs.z;
      const float u = a + b - a * b;
      un += u * s; ud += u;
    }
    {
      const float s = -p.w;
      const float a = __expf(s - rm) * ri;
      const float b = __expf(s - cm.w) / cs.w;
      const float u = a + b - a * b;
      un += u * s; ud += u;
    }
  }
  un = waveSum(un); ud = waveSum(ud);
  if ((t & 63) == 0) { redn[t >> 6] = un; redd[t >> 6] = ud; }
  __syncthreads();
  if (t == 0) {
    atomicAdd(&accum[0], redn[0] + redn[1] + redn[2] + redn[3]);
    atomicAdd(&accum[1], redd[0] + redd[1] + redd[2] + redd[3]);
  }
}

__global__ void finalize_kernel(const float* __restrict__ accum, float* __restrict__ out) {
  out[0] = accum[0] / accum[1];
}

// ---------------- fallback path (R2, ws >= ~148 KB, proven) ----------------

#define TJ  128
#define NCH (NN / TJ)
#define BLK 256

__global__ __launch_bounds__(BLK)
void stats2_kernel(const float* __restrict__ zx, const float* __restrict__ zy,
                   float* __restrict__ partM, float* __restrict__ partS) {
  const int side = blockIdx.z;
  const float* __restrict__ X = side ? zy : zx;
  const float* __restrict__ Y = side ? zx : zy;
  const int j0 = blockIdx.x * TJ;
  const int i0 = blockIdx.y * 8;
  const int t  = threadIdx.x;
  const int rg = t >> 5;
  const int c  = t & 31;

  __shared__ float xs[8 * DD];
  for (int k = t; k < 8 * DD; k += BLK)
    xs[k] = X[(k >> 3) * NN + i0 + (k & 7)];
  __syncthreads();

  const float4* __restrict__ Y4 = (const float4*)Y;
  const int yb = (j0 >> 2) + c;
  float4 acc = make_float4(0.f, 0.f, 0.f, 0.f);
  #pragma unroll 8
  for (int d = 0; d < DD; ++d) {
    const float4 yv = Y4[d * (NN / 4) + yb];
    const float xv = xs[d * 8 + rg];
    acc.x += fabsf(xv - yv.x);
    acc.y += fabsf(xv - yv.y);
    acc.z += fabsf(xv - yv.z);
    acc.w += fabsf(xv - yv.w);
  }

  float m = fmaxf(fmaxf(-acc.x, -acc.y), fmaxf(-acc.z, -acc.w));
  #pragma unroll
  for (int off = 16; off > 0; off >>= 1) m = fmaxf(m, __shfl_xor(m, off, 32));
  float p = __expf(-acc.x - m) + __expf(-acc.y - m) +
            __expf(-acc.z - m) + __expf(-acc.w - m);
  #pragma unroll
  for (int off = 16; off > 0; off >>= 1) p += __shfl_xor(p, off, 32);

  if (c == 0) {
    const int idx = side * (NCH * NN) + blockIdx.x * NN + (i0 + rg);
    partM[idx] = m;
    partS[idx] = p;
  }
}

__global__ __launch_bounds__(BLK)
void combine_kernel(const float* __restrict__ partM, const float* __restrict__ partS,
                    float* __restrict__ rmax, float* __restrict__ rsum,
                    float* __restrict__ cmax, float* __restrict__ csum,
                    float* __restrict__ accum) {
  const int gid = blockIdx.x * BLK + threadIdx.x;
  if (gid == 0) { accum[0] = 0.f; accum[1] = 0.f; }
  const int sd = gid >> 10;
  const int i  = gid & (NN - 1);
  float mk[NCH], sk[NCH];
  #pragma unroll
  for (int k = 0; k < NCH; ++k) {
    mk[k] = partM[sd * (NCH * NN) + k * NN + i];
    sk[k] = partS[sd * (NCH * NN) + k * NN + i];
  }
  float m = mk[0];
  #pragma unroll
  for (int k = 1; k < NCH; ++k) m = fmaxf(m, mk[k]);
  float s = 0.f;
  #pragma unroll
  for (int k = 0; k < NCH; ++k) s += __expf(mk[k] - m) * sk[k];
  if (sd == 0) { rmax[i] = m; rsum[i] = s; }
  else         { cmax[i] = m; csum[i] = s; }
}

__global__ __launch_bounds__(BLK)
void final2_kernel(const float* __restrict__ zx, const float* __restrict__ zy,
                   const float* __restrict__ rmax, const float* __restrict__ rsum,
                   const float* __restrict__ cmax, const float* __restrict__ csum,
                   float* __restrict__ accum) {
  const int j0 = blockIdx.x * TJ;
  const int i0 = blockIdx.y * 8;
  const int t  = threadIdx.x;
  const int rg = t >> 5;
  const int c  = t & 31;

  __shared__ float xs[8 * DD];
  __shared__ float redn[4], redd[4];
  for (int k = t; k < 8 * DD; k += BLK)
    xs[k] = zx[(k >> 3) * NN + i0 + (k & 7)];
  __syncthreads();

  const float4* __restrict__ Y4 = (const float4*)zy;
  const int yb = (j0 >> 2) + c;
  float4 acc = make_float4(0.f, 0.f, 0.f, 0.f);
  #pragma unroll 8
  for (int d = 0; d < DD; ++d) {
    const float4 yv = Y4[d * (NN / 4) + yb];
    const float xv = xs[d * 8 + rg];
    acc.x += fabsf(xv - yv.x);
    acc.y += fabsf(xv - yv.y);
    acc.z += fabsf(xv - yv.z);
    acc.w += fabsf(xv - yv.w);
  }

  const int i = i0 + rg;
  const float rm = rmax[i];
  const float ri = 1.f / rsum[i];
  const float4 cm = ((const float4*)cmax)[yb];
  const float4 cs = ((const float4*)csum)[yb];

  float un = 0.f, ud = 0.f;
  {
    const float s = -acc.x;
    const float a = __expf(s - rm) * ri;
    const float b = __expf(s - cm.x) / cs.x;
    const float u = a + b - a * b;
    un += u * s; ud += u;
  }
  {
    const float s = -acc.y;
    const float a = __expf(s - rm) * ri;
    const float b = __expf(s - cm.y) / cs.y;
    const float u = a + b - a * b;
    un += u * s; ud += u;
  }
  {
    const float s = -acc.z;
    const float a = __expf(s - rm) * ri;
    const float b = __expf(s - cm.z) / cs.z;
    const float u = a + b - a * b;
    un += u * s; ud += u;
  }
  {
    const float s = -acc.w;
    const float a = __expf(s - rm) * ri;
    const float b = __expf(s - cm.w) / cs.w;
    const float u = a + b - a * b;
    un += u * s; ud += u;
  }

  un = waveSum(un); ud = waveSum(ud);
  if ((t & 63) == 0) { redn[t >> 6] = un; redd[t >> 6] = ud; }
  __syncthreads();
  if (t == 0) {
    atomicAdd(&accum[0], redn[0] + redn[1] + redn[2] + redn[3]);
    atomicAdd(&accum[1], redd[0] + redd[1] + redd[2] + redd[3]);
  }
}

// ---------------------------------------------------------------------------

extern "C" void kernel_launch(void* const* d_in, const int* in_sizes, int n_in,
                              void* d_out, int out_size, void* d_ws, size_t ws_size,
                              hipStream_t stream) {
  const float* zx = (const float*)d_in[0];
  const float* zy = (const float*)d_in[1];
  float* ws  = (float*)d_ws;
  float* out = (float*)d_out;

  // fast-path ws layout (floats)
  float* accum = ws;
  float* Sp    = ws + 16;                    // DS * 1M
  float* pm    = Sp + DS * NN * NN;          // 64*1024
  float* ps    = pm + 64 * NN;               // 64*1024
  float* rmax  = ps + 64 * NN;
  float* rsum  = rmax + NN;
  float* cmax  = rsum + NN;
  float* csum  = cmax + NN;
  const size_t need = (size_t)((csum + NN) - ws) * sizeof(float);  // ~17.3 MB

  if (ws_size >= need) {
    dim3 g1(NN / 128, NN / 64, DS);          // 512 blocks
    scompute_kernel<<<g1, 256, 0, stream>>>(zx, zy, Sp, accum);
    rowstats_kernel<<<NN / 4, 256, 0, stream>>>(Sp, rmax, rsum);
    colstats_kernel<<<NN / 16, 256, 0, stream>>>(Sp, pm, ps);
    colcombine_kernel<<<NN / 256, 256, 0, stream>>>(pm, ps, cmax, csum);
    final_kernel<<<NN / 4, 256, 0, stream>>>(Sp, rmax, rsum, cmax, csum, accum);
    finalize_kernel<<<1, 1, 0, stream>>>(accum, out);
  } else {
    // R2 fallback (~148 KB)
    float* partM = ws + 16;
    float* partS = partM + 2 * NCH * NN;
    float* frmax = partS + 2 * NCH * NN;
    float* frsum = frmax + NN;
    float* fcmax = frsum + NN;
    float* fcsum = fcmax + NN;
    dim3 sgrid(NCH, NN / 8, 2);
    stats2_kernel<<<sgrid, BLK, 0, stream>>>(zx, zy, partM, partS);
    combine_kernel<<<(2 * NN) / BLK, BLK, 0, stream>>>(partM, partS,
                                                       frmax, frsum, fcmax, fcsum, accum);
    dim3 fgrid(NCH, NN / 8);
    final2_kernel<<<fgrid, BLK, 0, stream>>>(zx, zy, frmax, frsum, fcmax, fcsum, accum);
    finalize_kernel<<<1, 1, 0, stream>>>(accum, out);
  }
}

// Round 4
// 124.470 us; speedup vs baseline: 1.9620x; 1.0057x over previous
//
#include <hip/hip_runtime.h>
#include <math.h>

// SSAaligner: s[i,j] = -sum_d |x[i,d]-y[j,d]|, x from z_x(D,N), y from z_y(D,M)
// a = softmax_rows(s), b = softmax_cols(s), u = a+b-a*b, out = sum(u*s)/sum(u)
// D=256, N=M=1024. fp32 in, fp32 scalar out.
//
// R4: scompute with explicit 4-deep y-load pipeline + __launch_bounds__(256,2)
// (R3's compiler rolled the loop to 36 VGPR -> vmcnt(0) serialization, 30% VALU).
// Fused row+col stats pass; last-block finalize. 4 launches total.

#define DD 256
#define NN 1024
#define DS 4
#define CH (DD / DS)   // 64 d's per chunk
#define NQ (NN / 4)    // 256 float4 per row

// ---------------- reductions ----------------
__device__ __forceinline__ float waveMax(float v) {
  #pragma unroll
  for (int off = 32; off; off >>= 1) v = fmaxf(v, __shfl_xor(v, off, 64));
  return v;
}
__device__ __forceinline__ float waveSum(float v) {
  #pragma unroll
  for (int off = 32; off; off >>= 1) v += __shfl_xor(v, off, 64);
  return v;
}
__device__ __forceinline__ float blockMax(float v, float* red) {
  v = waveMax(v);
  __syncthreads();
  if ((threadIdx.x & 63) == 0) red[threadIdx.x >> 6] = v;
  __syncthreads();
  return fmaxf(fmaxf(red[0], red[1]), fmaxf(red[2], red[3]));
}
__device__ __forceinline__ float blockSum(float v, float* red) {
  v = waveSum(v);
  __syncthreads();
  if ((threadIdx.x & 63) == 0) red[threadIdx.x >> 6] = v;
  __syncthreads();
  return red[0] + red[1] + red[2] + red[3];
}

// ---------------- fast path ----------------

// Tile 32 rows x 256 cols x 64 d. Thread: 8 rows x 4 cols. Full-wave coalesced
// 1KB y loads, 4-deep explicit prefetch pipeline. Grid (4,32,4)=512 blocks ->
// 2 blocks/CU, 8 waves/CU; launch_bounds(256,2) gives a 256-VGPR budget so the
// pipeline regs stay live.
#define SSTEP(YB, dd)                                                          \
  {                                                                            \
    const float* xp_ = xs + (dd) * 32 + g * 8;                                 \
    const float4 xa = *(const float4*)xp_;                                     \
    const float4 xb = *(const float4*)(xp_ + 4);                               \
    acc[0][0] += fabsf(xa.x - YB.x); acc[0][1] += fabsf(xa.x - YB.y);          \
    acc[0][2] += fabsf(xa.x - YB.z); acc[0][3] += fabsf(xa.x - YB.w);          \
    acc[1][0] += fabsf(xa.y - YB.x); acc[1][1] += fabsf(xa.y - YB.y);          \
    acc[1][2] += fabsf(xa.y - YB.z); acc[1][3] += fabsf(xa.y - YB.w);          \
    acc[2][0] += fabsf(xa.z - YB.x); acc[2][1] += fabsf(xa.z - YB.y);          \
    acc[2][2] += fabsf(xa.z - YB.z); acc[2][3] += fabsf(xa.z - YB.w);          \
    acc[3][0] += fabsf(xa.w - YB.x); acc[3][1] += fabsf(xa.w - YB.y);          \
    acc[3][2] += fabsf(xa.w - YB.z); acc[3][3] += fabsf(xa.w - YB.w);          \
    acc[4][0] += fabsf(xb.x - YB.x); acc[4][1] += fabsf(xb.x - YB.y);          \
    acc[4][2] += fabsf(xb.x - YB.z); acc[4][3] += fabsf(xb.x - YB.w);          \
    acc[5][0] += fabsf(xb.y - YB.x); acc[5][1] += fabsf(xb.y - YB.y);          \
    acc[5][2] += fabsf(xb.y - YB.z); acc[5][3] += fabsf(xb.y - YB.w);          \
    acc[6][0] += fabsf(xb.z - YB.x); acc[6][1] += fabsf(xb.z - YB.y);          \
    acc[6][2] += fabsf(xb.z - YB.z); acc[6][3] += fabsf(xb.z - YB.w);          \
    acc[7][0] += fabsf(xb.w - YB.x); acc[7][1] += fabsf(xb.w - YB.y);          \
    acc[7][2] += fabsf(xb.w - YB.z); acc[7][3] += fabsf(xb.w - YB.w);          \
    const int dn_ = ((dd) + 4 < CH) ? (dd) + 4 : CH - 1;                       \
    YB = yp[dn_ * NQ];                                                         \
  }

__global__ __launch_bounds__(256, 2)
void scompute_kernel(const float* __restrict__ zx, const float* __restrict__ zy,
                     float* __restrict__ Sp, float* __restrict__ accum) {
  const int h  = blockIdx.z;
  const int i0 = blockIdx.y * 32;
  const int j0 = blockIdx.x * 256;
  const int t  = threadIdx.x;
  const int g  = t >> 6;   // row group 0..3 (8 rows each)
  const int c  = t & 63;   // col quad within tile (64 quads = 256 cols)
  if (t == 0 && (blockIdx.x | blockIdx.y | blockIdx.z) == 0) {
    accum[0] = 0.f; accum[1] = 0.f; ((unsigned int*)accum)[2] = 0u;
  }

  __shared__ float xs[CH * 32];   // xs[d*32 + r]
  {
    const float4* __restrict__ X4 = (const float4*)zx;
    float4* xs4 = (float4*)xs;
    #pragma unroll
    for (int k = t; k < CH * 8; k += 256) {
      const int dd = k >> 3, rq = k & 7;
      xs4[k] = X4[(h * CH + dd) * NQ + (i0 >> 2) + rq];
    }
  }
  __syncthreads();

  float acc[8][4];
  #pragma unroll
  for (int r = 0; r < 8; ++r)
    #pragma unroll
    for (int q = 0; q < 4; ++q) acc[r][q] = 0.f;

  const float4* __restrict__ yp =
      (const float4*)zy + (size_t)(h * CH) * NQ + (j0 >> 2) + c;
  float4 y0 = yp[0 * NQ];
  float4 y1 = yp[1 * NQ];
  float4 y2 = yp[2 * NQ];
  float4 y3 = yp[3 * NQ];

  #pragma unroll 1
  for (int d = 0; d < CH; d += 4) {
    SSTEP(y0, d + 0)
    SSTEP(y1, d + 1)
    SSTEP(y2, d + 2)
    SSTEP(y3, d + 3)
  }

  float4* __restrict__ S4 = (float4*)Sp + (size_t)h * (NN * NQ);
  #pragma unroll
  for (int r = 0; r < 8; ++r)
    S4[(i0 + g * 8 + r) * NQ + (j0 >> 2) + c] =
        make_float4(acc[r][0], acc[r][1], acc[r][2], acc[r][3]);
}

// 256 blocks x 4 rows: sum the 4 partial slabs (write S back to slab0),
// full row max/sumexp, AND per-4-row-stripe column partials (pm/ps).
__global__ __launch_bounds__(256)
void rowcolstats_kernel(float* __restrict__ Sp,
                        float* __restrict__ rmax, float* __restrict__ rsum,
                        float* __restrict__ pm, float* __restrict__ ps) {
  __shared__ float red[4];
  const int t = threadIdx.x;
  const int row0 = blockIdx.x * 4;
  float4* S4 = (float4*)Sp;
  float4 p[4];
  #pragma unroll
  for (int r = 0; r < 4; ++r) {
    float4 v = S4[(row0 + r) * NQ + t];
    #pragma unroll
    for (int hh = 1; hh < DS; ++hh) {
      const float4 q = S4[(size_t)hh * (NN * NQ) + (row0 + r) * NQ + t];
      v.x += q.x; v.y += q.y; v.z += q.z; v.w += q.w;
    }
    S4[(row0 + r) * NQ + t] = v;
    p[r] = v;
  }
  // row stats
  #pragma unroll
  for (int r = 0; r < 4; ++r) {
    float m = fmaxf(fmaxf(-p[r].x, -p[r].y), fmaxf(-p[r].z, -p[r].w));
    m = blockMax(m, red);
    float l = __expf(-p[r].x - m) + __expf(-p[r].y - m) +
              __expf(-p[r].z - m) + __expf(-p[r].w - m);
    l = blockSum(l, red);
    if (t == 0) { rmax[row0 + r] = m; rsum[row0 + r] = l; }
  }
  // column partials over this 4-row stripe
  float4 cm = make_float4(-1e30f, -1e30f, -1e30f, -1e30f);
  #pragma unroll
  for (int r = 0; r < 4; ++r) {
    cm.x = fmaxf(cm.x, -p[r].x); cm.y = fmaxf(cm.y, -p[r].y);
    cm.z = fmaxf(cm.z, -p[r].z); cm.w = fmaxf(cm.w, -p[r].w);
  }
  float4 cl = make_float4(0.f, 0.f, 0.f, 0.f);
  #pragma unroll
  for (int r = 0; r < 4; ++r) {
    cl.x += __expf(-p[r].x - cm.x); cl.y += __expf(-p[r].y - cm.y);
    cl.z += __expf(-p[r].z - cm.z); cl.w += __expf(-p[r].w - cm.w);
  }
  ((float4*)pm)[blockIdx.x * NQ + t] = cm;
  ((float4*)ps)[blockIdx.x * NQ + t] = cl;
}

// Merge the 256 stripe-partials per column. 16 blocks x 64 cols.
__global__ __launch_bounds__(256)
void colcombine_kernel(const float* __restrict__ pm, const float* __restrict__ ps,
                       float* __restrict__ cmax, float* __restrict__ csum) {
  __shared__ float sm[4][64], sl[4][64];
  const int t  = threadIdx.x;
  const int jl = t & 63;
  const int pc = t >> 6;           // partial chunk 0..3 (64 stripes each)
  const int j  = blockIdx.x * 64 + jl;
  float m = -1e30f;
  #pragma unroll 8
  for (int k = 0; k < 64; ++k) m = fmaxf(m, pm[(pc * 64 + k) * NN + j]);
  float l = 0.f;
  #pragma unroll 8
  for (int k = 0; k < 64; ++k)
    l += __expf(pm[(pc * 64 + k) * NN + j] - m) * ps[(pc * 64 + k) * NN + j];
  sm[pc][jl] = m; sl[pc][jl] = l;
  __syncthreads();
  if (pc == 0) {
    float M = fmaxf(fmaxf(sm[0][jl], sm[1][jl]), fmaxf(sm[2][jl], sm[3][jl]));
    float L = sl[0][jl] * __expf(sm[0][jl] - M) + sl[1][jl] * __expf(sm[1][jl] - M) +
              sl[2][jl] * __expf(sm[2][jl] - M) + sl[3][jl] * __expf(sm[3][jl] - M);
    cmax[j] = M; csum[j] = L;
  }
}

// 256 blocks x 4 rows: u = a+b-a*b, reduce, atomic; LAST block divides.
__global__ __launch_bounds__(256)
void final_kernel(const float* __restrict__ Sp,
                  const float* __restrict__ rmax, const float* __restrict__ rsum,
                  const float* __restrict__ cmax, const float* __restrict__ csum,
                  float* __restrict__ accum, float* __restrict__ out) {
  __shared__ float redn[4], redd[4];
  const int t = threadIdx.x;
  const int row0 = blockIdx.x * 4;
  const float4* S4 = (const float4*)Sp;
  const float4 cm = ((const float4*)cmax)[t];
  const float4 cs = ((const float4*)csum)[t];
  float un = 0.f, ud = 0.f;
  #pragma unroll
  for (int r = 0; r < 4; ++r) {
    const int row = row0 + r;
    const float rm = rmax[row];
    const float ri = 1.f / rsum[row];
    const float4 p = S4[row * NQ + t];
    {
      const float s = -p.x;
      const float a = __expf(s - rm) * ri;
      const float b = __expf(s - cm.x) / cs.x;
      const float u = a + b - a * b;
      un += u * s; ud += u;
    }
    {
      const float s = -p.y;
      const float a = __expf(s - rm) * ri;
      const float b = __expf(s - cm.y) / cs.y;
      const float u = a + b - a * b;
      un += u * s; ud += u;
    }
    {
      const float s = -p.z;
      const float a = __expf(s - rm) * ri;
      const float b = __expf(s - cm.z) / cs.z;
      const float u = a + b - a * b;
      un += u * s; ud += u;
    }
    {
      const float s = -p.w;
      const float a = __expf(s - rm) * ri;
      const float b = __expf(s - cm.w) / cs.w;
      const float u = a + b - a * b;
      un += u * s; ud += u;
    }
  }
  un = waveSum(un); ud = waveSum(ud);
  if ((t & 63) == 0) { redn[t >> 6] = un; redd[t >> 6] = ud; }
  __syncthreads();
  if (t == 0) {
    atomicAdd(&accum[0], redn[0] + redn[1] + redn[2] + redn[3]);
    atomicAdd(&accum[1], redd[0] + redd[1] + redd[2] + redd[3]);
    __threadfence();
    unsigned int* cnt = (unsigned int*)accum + 2;
    const unsigned int old = atomicAdd(cnt, 1u);
    if (old == gridDim.x - 1) {
      const float n = atomicAdd(&accum[0], 0.f);
      const float d = atomicAdd(&accum[1], 0.f);
      out[0] = n / d;
    }
  }
}

// ---------------- fallback path (R2, ws >= ~148 KB, proven) ----------------

#define TJ  128
#define NCH (NN / TJ)
#define BLK 256

__global__ __launch_bounds__(BLK)
void stats2_kernel(const float* __restrict__ zx, const float* __restrict__ zy,
                   float* __restrict__ partM, float* __restrict__ partS) {
  const int side = blockIdx.z;
  const float* __restrict__ X = side ? zy : zx;
  const float* __restrict__ Y = side ? zx : zy;
  const int j0 = blockIdx.x * TJ;
  const int i0 = blockIdx.y * 8;
  const int t  = threadIdx.x;
  const int rg = t >> 5;
  const int c  = t & 31;

  __shared__ float xs[8 * DD];
  for (int k = t; k < 8 * DD; k += BLK)
    xs[k] = X[(k >> 3) * NN + i0 + (k & 7)];
  __syncthreads();

  const float4* __restrict__ Y4 = (const float4*)Y;
  const int yb = (j0 >> 2) + c;
  float4 acc = make_float4(0.f, 0.f, 0.f, 0.f);
  #pragma unroll 8
  for (int d = 0; d < DD; ++d) {
    const float4 yv = Y4[d * NQ + yb];
    const float xv = xs[d * 8 + rg];
    acc.x += fabsf(xv - yv.x);
    acc.y += fabsf(xv - yv.y);
    acc.z += fabsf(xv - yv.z);
    acc.w += fabsf(xv - yv.w);
  }

  float m = fmaxf(fmaxf(-acc.x, -acc.y), fmaxf(-acc.z, -acc.w));
  #pragma unroll
  for (int off = 16; off > 0; off >>= 1) m = fmaxf(m, __shfl_xor(m, off, 32));
  float p = __expf(-acc.x - m) + __expf(-acc.y - m) +
            __expf(-acc.z - m) + __expf(-acc.w - m);
  #pragma unroll
  for (int off = 16; off > 0; off >>= 1) p += __shfl_xor(p, off, 32);

  if (c == 0) {
    const int idx = side * (NCH * NN) + blockIdx.x * NN + (i0 + rg);
    partM[idx] = m;
    partS[idx] = p;
  }
}

__global__ __launch_bounds__(BLK)
void combine_kernel(const float* __restrict__ partM, const float* __restrict__ partS,
                    float* __restrict__ rmax, float* __restrict__ rsum,
                    float* __restrict__ cmax, float* __restrict__ csum,
                    float* __restrict__ accum) {
  const int gid = blockIdx.x * BLK + threadIdx.x;
  if (gid == 0) { accum[0] = 0.f; accum[1] = 0.f; }
  const int sd = gid >> 10;
  const int i  = gid & (NN - 1);
  float mk[NCH], sk[NCH];
  #pragma unroll
  for (int k = 0; k < NCH; ++k) {
    mk[k] = partM[sd * (NCH * NN) + k * NN + i];
    sk[k] = partS[sd * (NCH * NN) + k * NN + i];
  }
  float m = mk[0];
  #pragma unroll
  for (int k = 1; k < NCH; ++k) m = fmaxf(m, mk[k]);
  float s = 0.f;
  #pragma unroll
  for (int k = 0; k < NCH; ++k) s += __expf(mk[k] - m) * sk[k];
  if (sd == 0) { rmax[i] = m; rsum[i] = s; }
  else         { cmax[i] = m; csum[i] = s; }
}

__global__ __launch_bounds__(BLK)
void final2_kernel(const float* __restrict__ zx, const float* __restrict__ zy,
                   const float* __restrict__ rmax, const float* __restrict__ rsum,
                   const float* __restrict__ cmax, const float* __restrict__ csum,
                   float* __restrict__ accum) {
  const int j0 = blockIdx.x * TJ;
  const int i0 = blockIdx.y * 8;
  const int t  = threadIdx.x;
  const int rg = t >> 5;
  const int c  = t & 31;

  __shared__ float xs[8 * DD];
  __shared__ float redn[4], redd[4];
  for (int k = t; k < 8 * DD; k += BLK)
    xs[k] = zx[(k >> 3) * NN + i0 + (k & 7)];
  __syncthreads();

  const float4* __restrict__ Y4 = (const float4*)zy;
  const int yb = (j0 >> 2) + c;
  float4 acc = make_float4(0.f, 0.f, 0.f, 0.f);
  #pragma unroll 8
  for (int d = 0; d < DD; ++d) {
    const float4 yv = Y4[d * NQ + yb];
    const float xv = xs[d * 8 + rg];
    acc.x += fabsf(xv - yv.x);
    acc.y += fabsf(xv - yv.y);
    acc.z += fabsf(xv - yv.z);
    acc.w += fabsf(xv - yv.w);
  }

  const int i = i0 + rg;
  const float rm = rmax[i];
  const float ri = 1.f / rsum[i];
  const float4 cm = ((const float4*)cmax)[yb];
  const float4 cs = ((const float4*)csum)[yb];

  float un = 0.f, ud = 0.f;
  {
    const float s = -acc.x;
    const float a = __expf(s - rm) * ri;
    const float b = __expf(s - cm.x) / cs.x;
    const float u = a + b - a * b;
    un += u * s; ud += u;
  }
  {
    const float s = -acc.y;
    const float a = __expf(s - rm) * ri;
    const float b = __expf(s - cm.y) / cs.y;
    const float u = a + b - a * b;
    un += u * s; ud += u;
  }
  {
    const float s = -acc.z;
    const float a = __expf(s - rm) * ri;
    const float b = __expf(s - cm.z) / cs.z;
    const float u = a + b - a * b;
    un += u * s; ud += u;
  }
  {
    const float s = -acc.w;
    const float a = __expf(s - rm) * ri;
    const float b = __expf(s - cm.w) / cs.w;
    const float u = a + b - a * b;
    un += u * s; ud += u;
  }

  un = waveSum(un); ud = waveSum(ud);
  if ((t & 63) == 0) { redn[t >> 6] = un; redd[t >> 6] = ud; }
  __syncthreads();
  if (t == 0) {
    atomicAdd(&accum[0], redn[0] + redn[1] + redn[2] + redn[3]);
    atomicAdd(&accum[1], redd[0] + redd[1] + redd[2] + redd[3]);
  }
}

__global__ void finalize_kernel(const float* __restrict__ accum, float* __restrict__ out) {
  out[0] = accum[0] / accum[1];
}

// ---------------------------------------------------------------------------

extern "C" void kernel_launch(void* const* d_in, const int* in_sizes, int n_in,
                              void* d_out, int out_size, void* d_ws, size_t ws_size,
                              hipStream_t stream) {
  const float* zx = (const float*)d_in[0];   // (1, D, N): X[d*N + i]
  const float* zy = (const float*)d_in[1];   // (1, D, M): Y[d*M + j]
  float* ws  = (float*)d_ws;
  float* out = (float*)d_out;

  // fast-path ws layout (floats)
  float* accum = ws;                         // [0]=num, [1]=den, [2]=ticket
  float* Sp    = ws + 16;                    // DS * 1M
  float* pm    = Sp + DS * NN * NN;          // 256*1024
  float* ps    = pm + 256 * NN;              // 256*1024
  float* rmax  = ps + 256 * NN;
  float* rsum  = rmax + NN;
  float* cmax  = rsum + NN;
  float* csum  = cmax + NN;
  const size_t need = (size_t)((csum + NN) - ws) * sizeof(float);  // ~19 MB

  if (ws_size >= need) {
    dim3 g1(NN / 256, NN / 32, DS);          // 512 blocks
    scompute_kernel<<<g1, 256, 0, stream>>>(zx, zy, Sp, accum);
    rowcolstats_kernel<<<NN / 4, 256, 0, stream>>>(Sp, rmax, rsum, pm, ps);
    colcombine_kernel<<<NN / 64, 256, 0, stream>>>(pm, ps, cmax, csum);
    final_kernel<<<NN / 4, 256, 0, stream>>>(Sp, rmax, rsum, cmax, csum, accum, out);
  } else {
    // R2 fallback (~148 KB)
    float* partM = ws + 16;
    float* partS = partM + 2 * NCH * NN;
    float* frmax = partS + 2 * NCH * NN;
    float* frsum = frmax + NN;
    float* fcmax = frsum + NN;
    float* fcsum = fcmax + NN;
    dim3 sgrid(NCH, NN / 8, 2);
    stats2_kernel<<<sgrid, BLK, 0, stream>>>(zx, zy, partM, partS);
    combine_kernel<<<(2 * NN) / BLK, BLK, 0, stream>>>(partM, partS,
                                                       frmax, frsum, fcmax, fcsum, accum);
    dim3 fgrid(NCH, NN / 8);
    final2_kernel<<<fgrid, BLK, 0, stream>>>(zx, zy, frmax, frsum, fcmax, fcsum, accum);
    finalize_kernel<<<1, 1, 0, stream>>>(accum, out);
  }
}